// Round 19
// baseline (366.964 us; speedup 1.0000x reference)
//
#include <hip/hip_runtime.h>
#include <stdint.h>

typedef __attribute__((ext_vector_type(8))) __bf16 bf16x8;
typedef __attribute__((ext_vector_type(4))) float f32x4;
typedef __attribute__((ext_vector_type(8))) unsigned short u16x8;
typedef __attribute__((ext_vector_type(4))) unsigned short u16x4;

#define SEQ 2048
#define HID 4608
#define NQKV 5632   // 4608 q + 512 k + 512 v
#define NHEAD 36
#define NKVH 4
#define HDIM 128
#define WINDOW 1024

__device__ __forceinline__ unsigned short f2b(float f) {
    unsigned u = __builtin_bit_cast(unsigned, f);
    u += 0x7fffu + ((u >> 16) & 1u);
    return (unsigned short)(u >> 16);
}
__device__ __forceinline__ float b2f(unsigned short h) {
    unsigned u = ((unsigned)h) << 16;
    return __builtin_bit_cast(float, u);
}

#define GLD16(gp, lp) __builtin_amdgcn_global_load_lds( \
    (const __attribute__((address_space(1))) void*)(gp), \
    (__attribute__((address_space(3))) void*)(lp), 16, 0, 0)

#define VMCNT8() asm volatile("s_waitcnt vmcnt(8)" ::: "memory")
#define VMCNT5() asm volatile("s_waitcnt vmcnt(5)" ::: "memory")
#define VMCNT4() asm volatile("s_waitcnt vmcnt(4)" ::: "memory")
#define VMCNT0() asm volatile("s_waitcnt vmcnt(0)" ::: "memory")
// HW barrier + COMPILER memory fence (raw builtin is IntrNoMem -> loads may hoist past it)
#define BARRIER() asm volatile("s_barrier" ::: "memory")

// ---------------- merged f32 -> bf16 convert (4 segments, one launch) ----------------
__global__ __launch_bounds__(256) void conv_all_kernel(
    const float* __restrict__ s0, unsigned short* __restrict__ d0, int n0,
    const float* __restrict__ s1, unsigned short* __restrict__ d1, int n1,
    const float* __restrict__ s2, unsigned short* __restrict__ d2, int n2,
    const float* __restrict__ s3, unsigned short* __restrict__ d3, int n3)
{
    int total = n0 + n1 + n2 + n3;
    int stride = gridDim.x * blockDim.x;
    for (int i = blockIdx.x * blockDim.x + threadIdx.x; i < total; i += stride) {
        const float* src; unsigned short* dst; int j = i;
        if (j < n0) { src = s0; dst = d0; }
        else if ((j -= n0) < n1) { src = s1; dst = d1; }
        else if ((j -= n1) < n2) { src = s2; dst = d2; }
        else { j -= n2; src = s3; dst = d3; }
        float4 v = ((const float4*)src)[j];
        ushort4 o;
        o.x = f2b(v.x); o.y = f2b(v.y); o.z = f2b(v.z); o.w = f2b(v.w);
        ((ushort4*)dst)[j] = o;
    }
}

// ---------------- GEMM 256x256, BK=64, 8 waves, 8-phase (R8-proven schedule) ----------------
// Blocks [0,GB) run the GEMM; blocks [GB,gridDim) grid-stride a f32->bf16 convert.
// The o_w conversion rides here (not on attn): the GEMM window is 151 us and not
// HBM-hungry, so the 80 rider blocks absorb the 286 MB conversion for free (R16/R17 A/B).
__global__ __launch_bounds__(512, 2) void gemm256_kernel(
    const unsigned short* __restrict__ A,
    const unsigned short* __restrict__ W,
    void* __restrict__ out,
    const float* __restrict__ b0, const float* __restrict__ b1, const float* __restrict__ b2,
    int N, int K, int GX, int GB, int outf32,
    const float* __restrict__ cw_src, unsigned short* __restrict__ cw_dst, int cw_n4)
{
    const int tid = threadIdx.x;
    const int o = blockIdx.x;

    if (o >= GB) {                      // ---- spare blocks: o_w f32->bf16 convert ----
        int cb = o - GB, ncb = gridDim.x - GB;
        int stride = ncb * 512;
        for (int i = cb * 512 + tid; i < cw_n4; i += stride) {
            float4 v = ((const float4*)cw_src)[i];
            ushort4 u;
            u.x = f2b(v.x); u.y = f2b(v.y); u.z = f2b(v.z); u.w = f2b(v.w);
            ((ushort4*)cw_dst)[i] = u;
        }
        return;
    }

    __shared__ alignas(16) unsigned short ldsA[2][256 * 64];
    __shared__ alignas(16) unsigned short ldsB[2][256 * 64];

    const int w = tid >> 6, lane = tid & 63;
    const int r16 = lane & 15, kg = lane >> 4;
    const int wm = w >> 2, wn = w & 3;          // 2M x 4N waves

    const int cpx = GB >> 3;
    const int id = (o & 7) * cpx + (o >> 3);
    const int bx = id % GX, by = id / GX;
    const int row0 = by * 256, col0 = bx * 256;

    const int lr = lane >> 3;
    const int lc = lane & 7;
    const int cg = lc ^ lr;            // pre-swizzled global chunk (rule #21)
    const unsigned short* Abase = A + (size_t)row0 * K;
    const unsigned short* Wbase = W + (size_t)col0 * K;

    auto STG = [&](const unsigned short* Mat, unsigned short* ldsSlot, int hf, int kb) {
#pragma unroll
        for (int j = 0; j < 2; ++j) {
            int row = hf * 128 + (w * 2 + j) * 8 + lr;
            GLD16(Mat + (size_t)row * K + kb + cg * 8,
                  (char*)ldsSlot + hf * 16384 + (w * 2 + j) * 1024);
        }
    };

    const int NITER = K >> 7;
    f32x4 acc[8][4] = {};
    const int swz = r16 & 7;

    bf16x8 af[4][2], bfA[2][2], bfB[2][2];

#define DSR_A(mh, Sl) \
_Pragma("unroll") for (int mi = 0; mi < 4; ++mi) \
_Pragma("unroll") for (int kh = 0; kh < 2; ++kh) \
    af[mi][kh] = *(const bf16x8*)((Sl) + (wm * 128 + (mh) * 64 + mi * 16 + r16) * 64 + ((kh * 4 + kg) ^ swz) * 8);
#define DSR_B(nh, Sl, BF) \
_Pragma("unroll") for (int ni = 0; ni < 2; ++ni) \
_Pragma("unroll") for (int kh = 0; kh < 2; ++kh) \
    BF[ni][kh] = *(const bf16x8*)((Sl) + (wn * 64 + (nh) * 32 + ni * 16 + r16) * 64 + ((kh * 4 + kg) ^ swz) * 8);
#define MFMA_Q(mh, nh, BF) \
    asm volatile("s_waitcnt lgkmcnt(0)" ::: "memory"); \
    __builtin_amdgcn_sched_barrier(0); \
    __builtin_amdgcn_s_setprio(1); \
_Pragma("unroll") for (int mi = 0; mi < 4; ++mi) \
_Pragma("unroll") for (int ni = 0; ni < 2; ++ni) \
_Pragma("unroll") for (int kh = 0; kh < 2; ++kh) \
    acc[(mh) * 4 + mi][(nh) * 2 + ni] = __builtin_amdgcn_mfma_f32_16x16x32_bf16(af[mi][kh], BF[ni][kh], acc[(mh) * 4 + mi][(nh) * 2 + ni], 0, 0, 0); \
    __builtin_amdgcn_s_setprio(0); \
    __builtin_amdgcn_sched_barrier(0);

    STG(Abase, ldsA[0], 0, 0);  STG(Abase, ldsA[0], 1, 0);
    STG(Wbase, ldsB[0], 0, 0);  STG(Wbase, ldsB[0], 1, 0);
    STG(Abase, ldsA[1], 0, 64); STG(Abase, ldsA[1], 1, 64);
    STG(Wbase, ldsB[1], 0, 64); STG(Wbase, ldsB[1], 1, 64);
    VMCNT0();
    BARRIER();

    for (int i = 0; i < NITER; ++i) {
        const unsigned short* A0 = ldsA[0];
        const unsigned short* B0 = ldsB[0];
        const unsigned short* A1 = ldsA[1];
        const unsigned short* B1 = ldsB[1];
        const bool st = (i + 1 < NITER);
        const int kb0 = (i + 1) * 128;
        const int kb1 = kb0 + 64;

        DSR_A(0, A0); DSR_B(0, B0, bfA);
        BARRIER();
        MFMA_Q(0, 0, bfA);
        BARRIER();
        DSR_B(1, B0, bfB);
        BARRIER();
        MFMA_Q(0, 1, bfB);
        BARRIER();
        DSR_A(1, A0);
        if (st) STG(Wbase, ldsB[0], 0, kb0);
        BARRIER();
        MFMA_Q(1, 1, bfB);
        BARRIER();
        if (st) { STG(Abase, ldsA[0], 0, kb0); VMCNT4(); } else { VMCNT0(); }
        BARRIER();
        MFMA_Q(1, 0, bfA);
        BARRIER();
        DSR_A(0, A1); DSR_B(0, B1, bfA);
        if (st) STG(Abase, ldsA[0], 1, kb0);
        BARRIER();
        MFMA_Q(0, 0, bfA);
        BARRIER();
        DSR_B(1, B1, bfB);
        if (st) STG(Wbase, ldsB[0], 1, kb0);
        BARRIER();
        MFMA_Q(0, 1, bfB);
        BARRIER();
        DSR_A(1, A1);
        if (st) { STG(Wbase, ldsB[1], 0, kb1); STG(Wbase, ldsB[1], 1, kb1); }
        BARRIER();
        MFMA_Q(1, 1, bfB);
        BARRIER();
        if (st) { STG(Abase, ldsA[1], 0, kb1); STG(Abase, ldsA[1], 1, kb1); VMCNT8(); }
        BARRIER();
        MFMA_Q(1, 0, bfA);
        BARRIER();
    }

    if (!outf32) {
        unsigned short* O = (unsigned short*)out;
#pragma unroll
        for (int m = 0; m < 8; ++m)
#pragma unroll
            for (int n = 0; n < 4; ++n)
#pragma unroll
                for (int r = 0; r < 4; ++r) {
                    int row = row0 + wm * 128 + m * 16 + kg * 4 + r;
                    int col = col0 + wn * 64 + n * 16 + r16;
                    float bias = (col < HID) ? b0[col]
                               : (col < HID + 512 ? b1[col - HID] : b2[col - HID - 512]);
                    O[(size_t)row * N + col] = f2b(acc[m][n][r] + bias);
                }
    } else {
        float* O = (float*)out;
#pragma unroll
        for (int m = 0; m < 8; ++m)
#pragma unroll
            for (int n = 0; n < 4; ++n)
#pragma unroll
                for (int r = 0; r < 4; ++r) {
                    int row = row0 + wm * 128 + m * 16 + kg * 4 + r;
                    int col = col0 + wn * 64 + n * 16 + r16;
                    O[(size_t)row * N + col] = acc[m][n][r] + b0[col];
                }
    }
#undef DSR_A
#undef DSR_B
#undef MFMA_Q
}

// ---------------- O-proj GEMM 128x192, BK=64, 8 waves, 4-phase, 2 blocks/CU ----------------
__global__ __launch_bounds__(512, 4) void gemm_op_kernel(
    const unsigned short* __restrict__ A,
    const unsigned short* __restrict__ W,
    float* __restrict__ out,
    const float* __restrict__ b0,
    int N, int K, int GX)
{
    __shared__ alignas(16) unsigned short ldsA[2][128 * 64];
    __shared__ alignas(16) unsigned short ldsB[2][192 * 64];

    const int tid = threadIdx.x;
    const int w = tid >> 6, lane = tid & 63;
    const int r16 = lane & 15, kg = lane >> 4;
    const int wm = w >> 2, wn = w & 3;

    const int cpx = gridDim.x >> 3;
    const int o = blockIdx.x;
    const int id = (o & 7) * cpx + (o >> 3);
    const int bx = id % GX, by = id / GX;
    const int row0 = by * 128, col0 = bx * 192;

    const int lr = lane >> 3;
    const int lc = lane & 7;
    const int cg = lc ^ lr;            // pre-swizzled global chunk (rule #21)
    const unsigned short* Abase = A + (size_t)row0 * K;
    const unsigned short* Wbase = W + (size_t)col0 * K;

    auto STGA = [&](unsigned short* slot, int kb) {
#pragma unroll
        for (int j = 0; j < 2; ++j) {
            int row = (w * 2 + j) * 8 + lr;
            GLD16(Abase + (size_t)row * K + kb + cg * 8,
                  (char*)slot + (w * 2 + j) * 1024);
        }
    };
    auto STGB = [&](unsigned short* slot, int kb) {
#pragma unroll
        for (int j3 = 0; j3 < 3; ++j3) {
            int row = j3 * 64 + w * 8 + lr;
            GLD16(Wbase + (size_t)row * K + kb + cg * 8,
                  (char*)slot + j3 * 8192 + w * 1024);
        }
    };

    const int NITER = K >> 7;
    f32x4 acc[4][3] = {};
    const int swz = r16 & 7;

    bf16x8 af[4][2], bf[3][2];

#define DSR_AF(Sl) \
_Pragma("unroll") for (int mi = 0; mi < 4; ++mi) \
_Pragma("unroll") for (int kh = 0; kh < 2; ++kh) \
    af[mi][kh] = *(const bf16x8*)((Sl) + (wm * 64 + mi * 16 + r16) * 64 + ((kh * 4 + kg) ^ swz) * 8);
#define DSR_BF(Sl) \
_Pragma("unroll") for (int ni = 0; ni < 3; ++ni) \
_Pragma("unroll") for (int kh = 0; kh < 2; ++kh) \
    bf[ni][kh] = *(const bf16x8*)((Sl) + (wn * 48 + ni * 16 + r16) * 64 + ((kh * 4 + kg) ^ swz) * 8);
#define MFMA12(half) \
    asm volatile("s_waitcnt lgkmcnt(0)" ::: "memory"); \
    __builtin_amdgcn_sched_barrier(0); \
    __builtin_amdgcn_s_setprio(1); \
_Pragma("unroll") for (int mi = 0; mi < 2; ++mi) \
_Pragma("unroll") for (int ni = 0; ni < 3; ++ni) \
_Pragma("unroll") for (int kh = 0; kh < 2; ++kh) \
    acc[(half) * 2 + mi][ni] = __builtin_amdgcn_mfma_f32_16x16x32_bf16(af[(half) * 2 + mi][kh], bf[ni][kh], acc[(half) * 2 + mi][ni], 0, 0, 0); \
    __builtin_amdgcn_s_setprio(0); \
    __builtin_amdgcn_sched_barrier(0);

    STGA(ldsA[0], 0);  STGB(ldsB[0], 0);
    STGA(ldsA[1], 64); STGB(ldsB[1], 64);
    VMCNT0();
    BARRIER();

    for (int i = 0; i < NITER; ++i) {
        const bool st = (i + 1 < NITER);
        const int kb0 = (i + 1) * 128;
        const int kb1 = kb0 + 64;

        DSR_AF(ldsA[0]); DSR_BF(ldsB[0]);
        BARRIER();
        MFMA12(0);
        BARRIER();
        if (st) { STGA(ldsA[0], kb0); STGB(ldsB[0], kb0); VMCNT5(); } else { VMCNT0(); }
        BARRIER();
        MFMA12(1);
        BARRIER();
        DSR_AF(ldsA[1]); DSR_BF(ldsB[1]);
        BARRIER();
        MFMA12(0);
        BARRIER();
        if (st) { STGA(ldsA[1], kb1); STGB(ldsB[1], kb1); VMCNT5(); }
        BARRIER();
        MFMA12(1);
        BARRIER();
    }

#pragma unroll
    for (int m = 0; m < 4; ++m)
#pragma unroll
        for (int n = 0; n < 3; ++n)
#pragma unroll
            for (int r = 0; r < 4; ++r) {
                int row = row0 + wm * 64 + m * 16 + kg * 4 + r;
                int col = col0 + wn * 48 + n * 16 + r16;
                out[(size_t)row * N + col] = acc[m][n][r] + b0[col];
            }
#undef DSR_AF
#undef DSR_BF
#undef MFMA12
}

// ---------------- fused RoPE (vectorized u16x4) + V transpose ----------------
__global__ __launch_bounds__(256) void rope_vt_kernel(unsigned short* __restrict__ qkv,
                                                      const float* __restrict__ cos_t,
                                                      const float* __restrict__ sin_t,
                                                      unsigned short* __restrict__ vtg) {
    const int bid = blockIdx.x;
    if (bid < 5120) {
        int idx = bid * 256 + threadIdx.x;      // SEQ*40*16 groups
        int d4 = idx & 15;
        int t2 = idx >> 4;
        int head = t2 % 40;
        int s = t2 / 40;
        int base = head < NHEAD ? head * HDIM : HID + (head - NHEAD) * HDIM;
        size_t off = (size_t)s * NQKV + base + d4 * 4;
        u16x4 xv = *(const u16x4*)(qkv + off);
        u16x4 yv = *(const u16x4*)(qkv + off + 64);
        float4 c = *(const float4*)(cos_t + s * HDIM + d4 * 4);
        float4 sn = *(const float4*)(sin_t + s * HDIM + d4 * 4);
        u16x4 xo, yo;
        float x, y;
        x = b2f(xv[0]); y = b2f(yv[0]); xo[0] = f2b(x * c.x - y * sn.x); yo[0] = f2b(y * c.x + x * sn.x);
        x = b2f(xv[1]); y = b2f(yv[1]); xo[1] = f2b(x * c.y - y * sn.y); yo[1] = f2b(y * c.y + x * sn.y);
        x = b2f(xv[2]); y = b2f(yv[2]); xo[2] = f2b(x * c.z - y * sn.z); yo[2] = f2b(y * c.z + x * sn.z);
        x = b2f(xv[3]); y = b2f(yv[3]); xo[3] = f2b(x * c.w - y * sn.w); yo[3] = f2b(y * c.w + x * sn.w);
        *(u16x4*)(qkv + off) = xo;
        *(u16x4*)(qkv + off + 64) = yo;
    } else {
        __shared__ unsigned short tile[32][36];
        int vb = bid - 5120;                    // 1024 blocks: 64 x 4 x 4
        const int s0 = (vb & 63) * 32;
        const int d0 = ((vb >> 6) & 3) * 32;
        const int kvh = vb >> 8;
        const int lid = threadIdx.x;
        {
            int sl = lid >> 3, dc = (lid & 7) * 4;
            u16x4 v = *(const u16x4*)(qkv + (size_t)(s0 + sl) * NQKV + HID + 512 + kvh * HDIM + d0 + dc);
#pragma unroll
            for (int i = 0; i < 4; ++i) tile[sl][dc + i] = v[i];
        }
        __syncthreads();
        {
            int dl = lid >> 3, sc = (lid & 7) * 4;
            u16x4 v;
#pragma unroll
            for (int i = 0; i < 4; ++i) v[i] = tile[sc + i][dl];
            *(u16x4*)(vtg + (size_t)kvh * HDIM * SEQ + (size_t)(d0 + dl) * SEQ + s0 + sc) = v;
        }
    }
}

// ---------------- flash attention, QBLK=64 + uniform-mask fast path ----------------
// Ps XOR-swizzle: row-groups kg={0,2} and {1,3} previously aliased on the same banks
// (4-way on every P-store: 4*44 dw == 16 mod 32). Flip the 16B granule on (row>>3)&1:
// write idx ^= (kg>>1)<<3, read idx ^= (r16>>3)<<3 — same involution both sides,
// 16B alignment preserved, conflicts drop to <=2-way (free per m136).
#define KSTR 136   // Ks row stride (u16): 272B = 68 dw ≡ 4 mod 32 -> 2-way free
#define VSTR 72    // Vt row stride (u16): 144B = 36 dw ≡ 4 mod 32 -> 2-way free
#define PSTR 88
__global__ __launch_bounds__(256) void attn_kernel(const unsigned short* __restrict__ qkv,
                                                   const unsigned short* __restrict__ vtg,
                                                   unsigned short* __restrict__ aout)
{
    __shared__ alignas(16) unsigned short Ks[64 * KSTR];
    __shared__ alignas(16) unsigned short Vt[128 * VSTR];
    __shared__ alignas(16) unsigned short Ps[4 * 16 * PSTR];
    const int h = blockIdx.x, qb = blockIdx.y;
    const int q0 = qb * 64;
    const int kvh = h / 9;
    const int tid = threadIdx.x, wid = tid >> 6, lane = tid & 63;
    const int r16 = lane & 15, kg = lane >> 4;
    const int qbase = q0 + wid * 16;
    const unsigned short* vsrc = vtg + (size_t)kvh * HDIM * SEQ;

    bf16x8 qf[4];
    {
        const unsigned short* qrow = qkv + (size_t)(qbase + r16) * NQKV + h * HDIM;
#pragma unroll
        for (int kk = 0; kk < 4; ++kk)
            qf[kk] = *(const bf16x8*)(qrow + kk * 32 + kg * 8);
    }

    f32x4 o[8] = {};
    float mrow[4], lrow[4];
#pragma unroll
    for (int r = 0; r < 4; ++r) { mrow[r] = -1e30f; lrow[r] = 0.f; }

    int lo = q0 - (WINDOW - 1); if (lo < 0) lo = 0; lo &= ~63;
    unsigned short* myP = Ps + wid * 16 * PSTR;
    const float scale = 0.08838834764831845f;
    const int pswz_w = (kg >> 1) << 3;          // write-side XOR (row = kg*4+r)
    const int pswz_r = (r16 >> 3) << 3;         // read-side XOR (row = r16)

    u16x8 kreg[4], vreg[4];
#define PREF(KT) \
_Pragma("unroll") for (int j = 0; j < 4; ++j) { \
        int c = tid + j * 256; \
        int key = c >> 4, dc = c & 15; \
        kreg[j] = *(const u16x8*)(qkv + (size_t)((KT) + key) * NQKV + HID + kvh * HDIM + dc * 8); \
        int d = c >> 3, k8 = (c & 7) * 8; \
        vreg[j] = *(const u16x8*)(vsrc + (size_t)d * SEQ + (KT) + k8); \
    }

    PREF(lo);

    for (int kt = lo; kt <= q0; kt += 64) {
#pragma unroll
        for (int j = 0; j < 4; ++j) {
            int c = tid + j * 256;
            int key = c >> 4, dc = c & 15;
            *(u16x8*)(Ks + key * KSTR + dc * 8) = kreg[j];
            int d = c >> 3, k8 = (c & 7) * 8;
            *(u16x8*)(Vt + d * VSTR + k8) = vreg[j];
        }
        __syncthreads();

        if (kt + 64 <= q0) { PREF(kt + 64); }

        f32x4 sc[4] = {};
#pragma unroll
        for (int t = 0; t < 4; ++t)
#pragma unroll
            for (int kk = 0; kk < 4; ++kk) {
                bf16x8 kf = *(const bf16x8*)(Ks + (t * 16 + r16) * KSTR + kk * 32 + kg * 8);
                sc[t] = __builtin_amdgcn_mfma_f32_16x16x32_bf16(qf[kk], kf, sc[t], 0, 0, 0);
            }

        float p[4][4], mt[4];
#pragma unroll
        for (int r = 0; r < 4; ++r) mt[r] = -1e30f;
        const bool fullv = (kt + 63 <= qbase) && (qbase + 15 - kt < WINDOW);
        if (fullv) {
#pragma unroll
            for (int t = 0; t < 4; ++t)
#pragma unroll
                for (int r = 0; r < 4; ++r) {
                    float v = sc[t][r] * scale;
                    p[t][r] = v;
                    mt[r] = fmaxf(mt[r], v);
                }
        } else {
#pragma unroll
            for (int t = 0; t < 4; ++t)
#pragma unroll
                for (int r = 0; r < 4; ++r) {
                    int q = qbase + kg * 4 + r;
                    int key = kt + t * 16 + r16;
                    bool valid = (key <= q) && (q - key < WINDOW);
                    float v = valid ? sc[t][r] * scale : -1e30f;
                    p[t][r] = v;
                    mt[r] = fmaxf(mt[r], v);
                }
        }
#pragma unroll
        for (int mask = 1; mask <= 8; mask <<= 1)
#pragma unroll
            for (int r = 0; r < 4; ++r)
                mt[r] = fmaxf(mt[r], __shfl_xor(mt[r], mask, 64));

        float alpha[4], tsum[4];
#pragma unroll
        for (int r = 0; r < 4; ++r) {
            float mnew = fmaxf(mrow[r], mt[r]);
            alpha[r] = __expf(mrow[r] - mnew);
            mrow[r] = mnew;
            tsum[r] = 0.f;
        }
#pragma unroll
        for (int t = 0; t < 4; ++t)
#pragma unroll
            for (int r = 0; r < 4; ++r) {
                float e = __expf(p[t][r] - mrow[r]);
                p[t][r] = e;
                tsum[r] += e;
            }
#pragma unroll
        for (int mask = 1; mask <= 8; mask <<= 1)
#pragma unroll
            for (int r = 0; r < 4; ++r)
                tsum[r] += __shfl_xor(tsum[r], mask, 64);
#pragma unroll
        for (int r = 0; r < 4; ++r)
            lrow[r] = lrow[r] * alpha[r] + tsum[r];
#pragma unroll
        for (int n = 0; n < 8; ++n)
#pragma unroll
            for (int r = 0; r < 4; ++r)
                o[n][r] = o[n][r] * alpha[r];

#pragma unroll
        for (int t = 0; t < 4; ++t)
#pragma unroll
            for (int r = 0; r < 4; ++r)
                myP[(((kg * 4 + r) * PSTR + t * 16 + r16)) ^ pswz_w] = f2b(p[t][r]);
        asm volatile("s_waitcnt lgkmcnt(0)" ::: "memory");

#pragma unroll
        for (int kc = 0; kc < 2; ++kc) {
            bf16x8 pa = *(const bf16x8*)(myP + ((r16 * PSTR + kc * 32 + kg * 8) ^ pswz_r));
#pragma unroll
            for (int n = 0; n < 8; ++n) {
                bf16x8 vb = *(const bf16x8*)(Vt + (n * 16 + r16) * VSTR + kc * 32 + kg * 8);
                o[n] = __builtin_amdgcn_mfma_f32_16x16x32_bf16(pa, vb, o[n], 0, 0, 0);
            }
        }
        BARRIER();                       // no vmcnt drain: keep prefetch in flight
    }
#undef PREF

#pragma unroll
    for (int n = 0; n < 8; ++n)
#pragma unroll
        for (int r = 0; r < 4; ++r) {
            int q = qbase + kg * 4 + r;
            aout[(size_t)q * HID + h * HDIM + n * 16 + r16] = f2b(o[n][r] / lrow[r]);
        }
}

extern "C" void kernel_launch(void* const* d_in, const int* in_sizes, int n_in,
                              void* d_out, int out_size, void* d_ws, size_t ws_size,
                              hipStream_t stream) {
    const float* hidden = (const float*)d_in[0];
    const float* cos_t = (const float*)d_in[2];
    const float* sin_t = (const float*)d_in[3];
    const float* q_w = (const float*)d_in[4];
    const float* q_b = (const float*)d_in[5];
    const float* k_w = (const float*)d_in[6];
    const float* k_b = (const float*)d_in[7];
    const float* v_w = (const float*)d_in[8];
    const float* v_b = (const float*)d_in[9];
    const float* o_w = (const float*)d_in[10];
    const float* o_b = (const float*)d_in[11];

    char* ws = (char*)d_ws;
    unsigned short* hbf  = (unsigned short*)ws;                   // 2048*4608 bf16
    unsigned short* attn = hbf;                                   // alias: reused after QKV GEMM
    unsigned short* wqkv = (unsigned short*)(ws + 18874368);      // 5632*4608 bf16 (dead after QKV GEMM)
    unsigned short* vtg  = wqkv;                                  // alias: V^T [4][128][2048]
    unsigned short* wo   = (unsigned short*)(ws + 70778880);      // 4608*4608 bf16
    unsigned short* qkv  = (unsigned short*)(ws + 113246208);     // 2048*5632 bf16

    dim3 blk(256);
    conv_all_kernel<<<4096, blk, 0, stream>>>(
        hidden, hbf,                          (SEQ * HID) / 4,
        q_w,    wqkv,                         (HID * HID) / 4,
        k_w,    wqkv + (size_t)HID * HID,     (512 * HID) / 4,
        v_w,    wqkv + (size_t)5120 * HID,    (512 * HID) / 4);

    // QKV GEMM on blocks 0..175; blocks 176..255 convert o_w concurrently.
    gemm256_kernel<<<dim3(256), dim3(512), 0, stream>>>(
        hbf, wqkv, qkv, q_b, k_b, v_b, NQKV, HID, 22, 176, 0,
        o_w, wo, (HID * HID) / 4);
    // fused RoPE + V-transpose (5120 rope blocks + 1024 vtrans blocks)
    rope_vt_kernel<<<6144, blk, 0, stream>>>(qkv, cos_t, sin_t, vtg);
    attn_kernel<<<dim3(NHEAD, SEQ / 64), blk, 0, stream>>>(qkv, vtg, attn);
    // O-proj: 128x192 tiles -> 16 x 24 = 384 blocks, 2 blocks/CU
    gemm_op_kernel<<<dim3(384), dim3(512), 0, stream>>>(
        attn, wo, (float*)d_out, o_b, HID, HID, 24);
}

// Round 20
// 363.409 us; speedup vs baseline: 1.0098x; 1.0098x over previous
//
#include <hip/hip_runtime.h>
#include <stdint.h>

typedef __attribute__((ext_vector_type(8))) __bf16 bf16x8;
typedef __attribute__((ext_vector_type(4))) float f32x4;
typedef __attribute__((ext_vector_type(8))) unsigned short u16x8;
typedef __attribute__((ext_vector_type(4))) unsigned short u16x4;

#define SEQ 2048
#define HID 4608
#define NQKV 5632   // 4608 q + 512 k + 512 v
#define NHEAD 36
#define NKVH 4
#define HDIM 128
#define WINDOW 1024

__device__ __forceinline__ unsigned short f2b(float f) {
    unsigned u = __builtin_bit_cast(unsigned, f);
    u += 0x7fffu + ((u >> 16) & 1u);
    return (unsigned short)(u >> 16);
}
__device__ __forceinline__ float b2f(unsigned short h) {
    unsigned u = ((unsigned)h) << 16;
    return __builtin_bit_cast(float, u);
}

#define GLD16(gp, lp) __builtin_amdgcn_global_load_lds( \
    (const __attribute__((address_space(1))) void*)(gp), \
    (__attribute__((address_space(3))) void*)(lp), 16, 0, 0)

#define VMCNT8() asm volatile("s_waitcnt vmcnt(8)" ::: "memory")
#define VMCNT5() asm volatile("s_waitcnt vmcnt(5)" ::: "memory")
#define VMCNT4() asm volatile("s_waitcnt vmcnt(4)" ::: "memory")
#define VMCNT0() asm volatile("s_waitcnt vmcnt(0)" ::: "memory")
// HW barrier + COMPILER memory fence (raw builtin is IntrNoMem -> loads may hoist past it)
#define BARRIER() asm volatile("s_barrier" ::: "memory")

// ---------------- merged f32 -> bf16 convert (4 segments, one launch) ----------------
__global__ __launch_bounds__(256) void conv_all_kernel(
    const float* __restrict__ s0, unsigned short* __restrict__ d0, int n0,
    const float* __restrict__ s1, unsigned short* __restrict__ d1, int n1,
    const float* __restrict__ s2, unsigned short* __restrict__ d2, int n2,
    const float* __restrict__ s3, unsigned short* __restrict__ d3, int n3)
{
    int total = n0 + n1 + n2 + n3;
    int stride = gridDim.x * blockDim.x;
    for (int i = blockIdx.x * blockDim.x + threadIdx.x; i < total; i += stride) {
        const float* src; unsigned short* dst; int j = i;
        if (j < n0) { src = s0; dst = d0; }
        else if ((j -= n0) < n1) { src = s1; dst = d1; }
        else if ((j -= n1) < n2) { src = s2; dst = d2; }
        else { j -= n2; src = s3; dst = d3; }
        float4 v = ((const float4*)src)[j];
        ushort4 o;
        o.x = f2b(v.x); o.y = f2b(v.y); o.z = f2b(v.z); o.w = f2b(v.w);
        ((ushort4*)dst)[j] = o;
    }
}

// ---------------- GEMM 256x256, BK=64, 8 waves, 8-phase (R8-proven schedule) ----------------
// Blocks [0,GB) run the GEMM; blocks [GB,gridDim) grid-stride a f32->bf16 convert.
// The o_w conversion rides here (not on attn): the GEMM window is 151 us and not
// HBM-hungry, so the 80 rider blocks absorb the 286 MB conversion for free (R16/R17 A/B).
__global__ __launch_bounds__(512, 2) void gemm256_kernel(
    const unsigned short* __restrict__ A,
    const unsigned short* __restrict__ W,
    void* __restrict__ out,
    const float* __restrict__ b0, const float* __restrict__ b1, const float* __restrict__ b2,
    int N, int K, int GX, int GB, int outf32,
    const float* __restrict__ cw_src, unsigned short* __restrict__ cw_dst, int cw_n4)
{
    const int tid = threadIdx.x;
    const int o = blockIdx.x;

    if (o >= GB) {                      // ---- spare blocks: o_w f32->bf16 convert ----
        int cb = o - GB, ncb = gridDim.x - GB;
        int stride = ncb * 512;
        for (int i = cb * 512 + tid; i < cw_n4; i += stride) {
            float4 v = ((const float4*)cw_src)[i];
            ushort4 u;
            u.x = f2b(v.x); u.y = f2b(v.y); u.z = f2b(v.z); u.w = f2b(v.w);
            ((ushort4*)cw_dst)[i] = u;
        }
        return;
    }

    __shared__ alignas(16) unsigned short ldsA[2][256 * 64];
    __shared__ alignas(16) unsigned short ldsB[2][256 * 64];

    const int w = tid >> 6, lane = tid & 63;
    const int r16 = lane & 15, kg = lane >> 4;
    const int wm = w >> 2, wn = w & 3;          // 2M x 4N waves

    const int cpx = GB >> 3;
    const int id = (o & 7) * cpx + (o >> 3);
    const int bx = id % GX, by = id / GX;
    const int row0 = by * 256, col0 = bx * 256;

    const int lr = lane >> 3;
    const int lc = lane & 7;
    const int cg = lc ^ lr;            // pre-swizzled global chunk (rule #21)
    const unsigned short* Abase = A + (size_t)row0 * K;
    const unsigned short* Wbase = W + (size_t)col0 * K;

    auto STG = [&](const unsigned short* Mat, unsigned short* ldsSlot, int hf, int kb) {
#pragma unroll
        for (int j = 0; j < 2; ++j) {
            int row = hf * 128 + (w * 2 + j) * 8 + lr;
            GLD16(Mat + (size_t)row * K + kb + cg * 8,
                  (char*)ldsSlot + hf * 16384 + (w * 2 + j) * 1024);
        }
    };

    const int NITER = K >> 7;
    f32x4 acc[8][4] = {};
    const int swz = r16 & 7;

    bf16x8 af[4][2], bfA[2][2], bfB[2][2];

#define DSR_A(mh, Sl) \
_Pragma("unroll") for (int mi = 0; mi < 4; ++mi) \
_Pragma("unroll") for (int kh = 0; kh < 2; ++kh) \
    af[mi][kh] = *(const bf16x8*)((Sl) + (wm * 128 + (mh) * 64 + mi * 16 + r16) * 64 + ((kh * 4 + kg) ^ swz) * 8);
#define DSR_B(nh, Sl, BF) \
_Pragma("unroll") for (int ni = 0; ni < 2; ++ni) \
_Pragma("unroll") for (int kh = 0; kh < 2; ++kh) \
    BF[ni][kh] = *(const bf16x8*)((Sl) + (wn * 64 + (nh) * 32 + ni * 16 + r16) * 64 + ((kh * 4 + kg) ^ swz) * 8);
#define MFMA_Q(mh, nh, BF) \
    asm volatile("s_waitcnt lgkmcnt(0)" ::: "memory"); \
    __builtin_amdgcn_sched_barrier(0); \
    __builtin_amdgcn_s_setprio(1); \
_Pragma("unroll") for (int mi = 0; mi < 4; ++mi) \
_Pragma("unroll") for (int ni = 0; ni < 2; ++ni) \
_Pragma("unroll") for (int kh = 0; kh < 2; ++kh) \
    acc[(mh) * 4 + mi][(nh) * 2 + ni] = __builtin_amdgcn_mfma_f32_16x16x32_bf16(af[mi][kh], BF[ni][kh], acc[(mh) * 4 + mi][(nh) * 2 + ni], 0, 0, 0); \
    __builtin_amdgcn_s_setprio(0); \
    __builtin_amdgcn_sched_barrier(0);

    STG(Abase, ldsA[0], 0, 0);  STG(Abase, ldsA[0], 1, 0);
    STG(Wbase, ldsB[0], 0, 0);  STG(Wbase, ldsB[0], 1, 0);
    STG(Abase, ldsA[1], 0, 64); STG(Abase, ldsA[1], 1, 64);
    STG(Wbase, ldsB[1], 0, 64); STG(Wbase, ldsB[1], 1, 64);
    VMCNT0();
    BARRIER();

    for (int i = 0; i < NITER; ++i) {
        const unsigned short* A0 = ldsA[0];
        const unsigned short* B0 = ldsB[0];
        const unsigned short* A1 = ldsA[1];
        const unsigned short* B1 = ldsB[1];
        const bool st = (i + 1 < NITER);
        const int kb0 = (i + 1) * 128;
        const int kb1 = kb0 + 64;

        DSR_A(0, A0); DSR_B(0, B0, bfA);
        BARRIER();
        MFMA_Q(0, 0, bfA);
        BARRIER();
        DSR_B(1, B0, bfB);
        BARRIER();
        MFMA_Q(0, 1, bfB);
        BARRIER();
        DSR_A(1, A0);
        if (st) STG(Wbase, ldsB[0], 0, kb0);
        BARRIER();
        MFMA_Q(1, 1, bfB);
        BARRIER();
        if (st) { STG(Abase, ldsA[0], 0, kb0); VMCNT4(); } else { VMCNT0(); }
        BARRIER();
        MFMA_Q(1, 0, bfA);
        BARRIER();
        DSR_A(0, A1); DSR_B(0, B1, bfA);
        if (st) STG(Abase, ldsA[0], 1, kb0);
        BARRIER();
        MFMA_Q(0, 0, bfA);
        BARRIER();
        DSR_B(1, B1, bfB);
        if (st) STG(Wbase, ldsB[0], 1, kb0);
        BARRIER();
        MFMA_Q(0, 1, bfB);
        BARRIER();
        DSR_A(1, A1);
        if (st) { STG(Wbase, ldsB[1], 0, kb1); STG(Wbase, ldsB[1], 1, kb1); }
        BARRIER();
        MFMA_Q(1, 1, bfB);
        BARRIER();
        if (st) { STG(Abase, ldsA[1], 0, kb1); STG(Abase, ldsA[1], 1, kb1); VMCNT8(); }
        BARRIER();
        MFMA_Q(1, 0, bfA);
        BARRIER();
    }

    if (!outf32) {
        unsigned short* O = (unsigned short*)out;
#pragma unroll
        for (int m = 0; m < 8; ++m)
#pragma unroll
            for (int n = 0; n < 4; ++n)
#pragma unroll
                for (int r = 0; r < 4; ++r) {
                    int row = row0 + wm * 128 + m * 16 + kg * 4 + r;
                    int col = col0 + wn * 64 + n * 16 + r16;
                    float bias = (col < HID) ? b0[col]
                               : (col < HID + 512 ? b1[col - HID] : b2[col - HID - 512]);
                    O[(size_t)row * N + col] = f2b(acc[m][n][r] + bias);
                }
    } else {
        float* O = (float*)out;
#pragma unroll
        for (int m = 0; m < 8; ++m)
#pragma unroll
            for (int n = 0; n < 4; ++n)
#pragma unroll
                for (int r = 0; r < 4; ++r) {
                    int row = row0 + wm * 128 + m * 16 + kg * 4 + r;
                    int col = col0 + wn * 64 + n * 16 + r16;
                    O[(size_t)row * N + col] = acc[m][n][r] + b0[col];
                }
    }
#undef DSR_A
#undef DSR_B
#undef MFMA_Q
}

// ---------------- O-proj GEMM 128x192, BK=64, 8 waves, 4-phase, 2 blocks/CU ----------------
// LDS = 2*(128+192)*64*2B = 80 KiB -> two co-resident blocks (m114 overlap).
// Waves 2M x 4N -> wave tile 64x48, acc[4][3]; 12-MFMA clusters (mi-halves).
// Per pair: phA reads ALL frags of tile t (14 ds_read_b128); phB stages that slot's
// next-pair data (A:2 + B:3 = 5 gloads) + vmcnt(5) -> retires exactly the slot read
// next (FIFO: 10 outstanding -> keep 5). Stage is always a barrier after last read.
__global__ __launch_bounds__(512, 4) void gemm_op_kernel(
    const unsigned short* __restrict__ A,
    const unsigned short* __restrict__ W,
    float* __restrict__ out,
    const float* __restrict__ b0,
    int N, int K, int GX)
{
    __shared__ alignas(16) unsigned short ldsA[2][128 * 64];
    __shared__ alignas(16) unsigned short ldsB[2][192 * 64];

    const int tid = threadIdx.x;
    const int w = tid >> 6, lane = tid & 63;
    const int r16 = lane & 15, kg = lane >> 4;
    const int wm = w >> 2, wn = w & 3;

    const int cpx = gridDim.x >> 3;
    const int o = blockIdx.x;
    const int id = (o & 7) * cpx + (o >> 3);
    const int bx = id % GX, by = id / GX;
    const int row0 = by * 128, col0 = bx * 192;

    const int lr = lane >> 3;
    const int lc = lane & 7;
    const int cg = lc ^ lr;            // pre-swizzled global chunk (rule #21)
    const unsigned short* Abase = A + (size_t)row0 * K;
    const unsigned short* Wbase = W + (size_t)col0 * K;

    auto STGA = [&](unsigned short* slot, int kb) {   // whole 128-row A tile: 2 loads
#pragma unroll
        for (int j = 0; j < 2; ++j) {
            int row = (w * 2 + j) * 8 + lr;
            GLD16(Abase + (size_t)row * K + kb + cg * 8,
                  (char*)slot + (w * 2 + j) * 1024);
        }
    };
    auto STGB = [&](unsigned short* slot, int kb) {   // whole 192-row B tile: 3 loads
#pragma unroll
        for (int j3 = 0; j3 < 3; ++j3) {
            int row = j3 * 64 + w * 8 + lr;
            GLD16(Wbase + (size_t)row * K + kb + cg * 8,
                  (char*)slot + j3 * 8192 + w * 1024);
        }
    };

    const int NITER = K >> 7;          // 64-wide K-tile pairs
    f32x4 acc[4][3] = {};
    const int swz = r16 & 7;

    bf16x8 af[4][2], bf[3][2];

#define DSR_AF(Sl) \
_Pragma("unroll") for (int mi = 0; mi < 4; ++mi) \
_Pragma("unroll") for (int kh = 0; kh < 2; ++kh) \
    af[mi][kh] = *(const bf16x8*)((Sl) + (wm * 64 + mi * 16 + r16) * 64 + ((kh * 4 + kg) ^ swz) * 8);
#define DSR_BF(Sl) \
_Pragma("unroll") for (int ni = 0; ni < 3; ++ni) \
_Pragma("unroll") for (int kh = 0; kh < 2; ++kh) \
    bf[ni][kh] = *(const bf16x8*)((Sl) + (wn * 48 + ni * 16 + r16) * 64 + ((kh * 4 + kg) ^ swz) * 8);
#define MFMA12(half) \
    asm volatile("s_waitcnt lgkmcnt(0)" ::: "memory"); \
    __builtin_amdgcn_sched_barrier(0); \
    __builtin_amdgcn_s_setprio(1); \
_Pragma("unroll") for (int mi = 0; mi < 2; ++mi) \
_Pragma("unroll") for (int ni = 0; ni < 3; ++ni) \
_Pragma("unroll") for (int kh = 0; kh < 2; ++kh) \
    acc[(half) * 2 + mi][ni] = __builtin_amdgcn_mfma_f32_16x16x32_bf16(af[(half) * 2 + mi][kh], bf[ni][kh], acc[(half) * 2 + mi][ni], 0, 0, 0); \
    __builtin_amdgcn_s_setprio(0); \
    __builtin_amdgcn_sched_barrier(0);

    // prologue: stage pair 0 fully (10 loads/thread)
    STGA(ldsA[0], 0);  STGB(ldsB[0], 0);
    STGA(ldsA[1], 64); STGB(ldsB[1], 64);
    VMCNT0();
    BARRIER();

    for (int i = 0; i < NITER; ++i) {
        const bool st = (i + 1 < NITER);
        const int kb0 = (i + 1) * 128;
        const int kb1 = kb0 + 64;

        // phA0: read all frags of tile t0; MFMA half 0
        DSR_AF(ldsA[0]); DSR_BF(ldsB[0]);
        BARRIER();
        MFMA12(0);
        BARRIER();
        // phB0: restage slot0; vmcnt(5) retires prev pair's slot1 loads; MFMA half 1
        if (st) { STGA(ldsA[0], kb0); STGB(ldsB[0], kb0); VMCNT5(); } else { VMCNT0(); }
        BARRIER();
        MFMA12(1);
        BARRIER();
        // phA1: read all frags of tile t1; MFMA half 0
        DSR_AF(ldsA[1]); DSR_BF(ldsB[1]);
        BARRIER();
        MFMA12(0);
        BARRIER();
        // phB1: restage slot1; vmcnt(5) retires this pair's slot0 loads; MFMA half 1
        if (st) { STGA(ldsA[1], kb1); STGB(ldsB[1], kb1); VMCNT5(); }
        BARRIER();
        MFMA12(1);
        BARRIER();
    }

    // epilogue: f32 + bias
#pragma unroll
    for (int m = 0; m < 4; ++m)
#pragma unroll
        for (int n = 0; n < 3; ++n)
#pragma unroll
            for (int r = 0; r < 4; ++r) {
                int row = row0 + wm * 64 + m * 16 + kg * 4 + r;
                int col = col0 + wn * 48 + n * 16 + r16;
                out[(size_t)row * N + col] = acc[m][n][r] + b0[col];
            }
#undef DSR_AF
#undef DSR_BF
#undef MFMA12
}

// ---------------- fused RoPE (vectorized u16x4) + V transpose ----------------
__global__ __launch_bounds__(256) void rope_vt_kernel(unsigned short* __restrict__ qkv,
                                                      const float* __restrict__ cos_t,
                                                      const float* __restrict__ sin_t,
                                                      unsigned short* __restrict__ vtg) {
    const int bid = blockIdx.x;
    if (bid < 5120) {
        int idx = bid * 256 + threadIdx.x;      // SEQ*40*16 groups
        int d4 = idx & 15;
        int t2 = idx >> 4;
        int head = t2 % 40;
        int s = t2 / 40;
        int base = head < NHEAD ? head * HDIM : HID + (head - NHEAD) * HDIM;
        size_t off = (size_t)s * NQKV + base + d4 * 4;
        u16x4 xv = *(const u16x4*)(qkv + off);
        u16x4 yv = *(const u16x4*)(qkv + off + 64);
        float4 c = *(const float4*)(cos_t + s * HDIM + d4 * 4);
        float4 sn = *(const float4*)(sin_t + s * HDIM + d4 * 4);
        u16x4 xo, yo;
        float x, y;
        x = b2f(xv[0]); y = b2f(yv[0]); xo[0] = f2b(x * c.x - y * sn.x); yo[0] = f2b(y * c.x + x * sn.x);
        x = b2f(xv[1]); y = b2f(yv[1]); xo[1] = f2b(x * c.y - y * sn.y); yo[1] = f2b(y * c.y + x * sn.y);
        x = b2f(xv[2]); y = b2f(yv[2]); xo[2] = f2b(x * c.z - y * sn.z); yo[2] = f2b(y * c.z + x * sn.z);
        x = b2f(xv[3]); y = b2f(yv[3]); xo[3] = f2b(x * c.w - y * sn.w); yo[3] = f2b(y * c.w + x * sn.w);
        *(u16x4*)(qkv + off) = xo;
        *(u16x4*)(qkv + off + 64) = yo;
    } else {
        __shared__ unsigned short tile[32][36];
        int vb = bid - 5120;                    // 1024 blocks: 64 x 4 x 4
        const int s0 = (vb & 63) * 32;
        const int d0 = ((vb >> 6) & 3) * 32;
        const int kvh = vb >> 8;
        const int lid = threadIdx.x;
        {
            int sl = lid >> 3, dc = (lid & 7) * 4;
            u16x4 v = *(const u16x4*)(qkv + (size_t)(s0 + sl) * NQKV + HID + 512 + kvh * HDIM + d0 + dc);
#pragma unroll
            for (int i = 0; i < 4; ++i) tile[sl][dc + i] = v[i];
        }
        __syncthreads();
        {
            int dl = lid >> 3, sc = (lid & 7) * 4;
            u16x4 v;
#pragma unroll
            for (int i = 0; i < 4; ++i) v[i] = tile[sc + i][dl];
            *(u16x4*)(vtg + (size_t)kvh * HDIM * SEQ + (size_t)(d0 + dl) * SEQ + s0 + sc) = v;
        }
    }
}

// ---------------- flash attention, QBLK=64 + uniform-mask fast path ----------------
#define KSTR 136   // Ks row stride (u16): 272B = 68 dw ≡ 4 mod 32 -> 2-way free
#define VSTR 72    // Vt row stride (u16): 144B = 36 dw ≡ 4 mod 32 -> 2-way free
#define PSTR 88
__global__ __launch_bounds__(256) void attn_kernel(const unsigned short* __restrict__ qkv,
                                                   const unsigned short* __restrict__ vtg,
                                                   unsigned short* __restrict__ aout)
{
    __shared__ alignas(16) unsigned short Ks[64 * KSTR];
    __shared__ alignas(16) unsigned short Vt[128 * VSTR];
    __shared__ alignas(16) unsigned short Ps[4 * 16 * PSTR];
    const int h = blockIdx.x, qb = blockIdx.y;
    const int q0 = qb * 64;
    const int kvh = h / 9;
    const int tid = threadIdx.x, wid = tid >> 6, lane = tid & 63;
    const int r16 = lane & 15, kg = lane >> 4;
    const int qbase = q0 + wid * 16;
    const unsigned short* vsrc = vtg + (size_t)kvh * HDIM * SEQ;

    bf16x8 qf[4];
    {
        const unsigned short* qrow = qkv + (size_t)(qbase + r16) * NQKV + h * HDIM;
#pragma unroll
        for (int kk = 0; kk < 4; ++kk)
            qf[kk] = *(const bf16x8*)(qrow + kk * 32 + kg * 8);
    }

    f32x4 o[8] = {};
    float mrow[4], lrow[4];
#pragma unroll
    for (int r = 0; r < 4; ++r) { mrow[r] = -1e30f; lrow[r] = 0.f; }

    int lo = q0 - (WINDOW - 1); if (lo < 0) lo = 0; lo &= ~63;
    unsigned short* myP = Ps + wid * 16 * PSTR;
    const float scale = 0.08838834764831845f;

    u16x8 kreg[4], vreg[4];
#define PREF(KT) \
_Pragma("unroll") for (int j = 0; j < 4; ++j) { \
        int c = tid + j * 256; \
        int key = c >> 4, dc = c & 15; \
        kreg[j] = *(const u16x8*)(qkv + (size_t)((KT) + key) * NQKV + HID + kvh * HDIM + dc * 8); \
        int d = c >> 3, k8 = (c & 7) * 8; \
        vreg[j] = *(const u16x8*)(vsrc + (size_t)d * SEQ + (KT) + k8); \
    }

    PREF(lo);

    for (int kt = lo; kt <= q0; kt += 64) {
#pragma unroll
        for (int j = 0; j < 4; ++j) {
            int c = tid + j * 256;
            int key = c >> 4, dc = c & 15;
            *(u16x8*)(Ks + key * KSTR + dc * 8) = kreg[j];
            int d = c >> 3, k8 = (c & 7) * 8;
            *(u16x8*)(Vt + d * VSTR + k8) = vreg[j];
        }
        __syncthreads();

        if (kt + 64 <= q0) { PREF(kt + 64); }

        f32x4 sc[4] = {};
#pragma unroll
        for (int t = 0; t < 4; ++t)
#pragma unroll
            for (int kk = 0; kk < 4; ++kk) {
                bf16x8 kf = *(const bf16x8*)(Ks + (t * 16 + r16) * KSTR + kk * 32 + kg * 8);
                sc[t] = __builtin_amdgcn_mfma_f32_16x16x32_bf16(qf[kk], kf, sc[t], 0, 0, 0);
            }

        float p[4][4], mt[4];
#pragma unroll
        for (int r = 0; r < 4; ++r) mt[r] = -1e30f;
        const bool fullv = (kt + 63 <= qbase) && (qbase + 15 - kt < WINDOW);
        if (fullv) {
#pragma unroll
            for (int t = 0; t < 4; ++t)
#pragma unroll
                for (int r = 0; r < 4; ++r) {
                    float v = sc[t][r] * scale;
                    p[t][r] = v;
                    mt[r] = fmaxf(mt[r], v);
                }
        } else {
#pragma unroll
            for (int t = 0; t < 4; ++t)
#pragma unroll
                for (int r = 0; r < 4; ++r) {
                    int q = qbase + kg * 4 + r;
                    int key = kt + t * 16 + r16;
                    bool valid = (key <= q) && (q - key < WINDOW);
                    float v = valid ? sc[t][r] * scale : -1e30f;
                    p[t][r] = v;
                    mt[r] = fmaxf(mt[r], v);
                }
        }
#pragma unroll
        for (int mask = 1; mask <= 8; mask <<= 1)
#pragma unroll
            for (int r = 0; r < 4; ++r)
                mt[r] = fmaxf(mt[r], __shfl_xor(mt[r], mask, 64));

        float alpha[4], tsum[4];
#pragma unroll
        for (int r = 0; r < 4; ++r) {
            float mnew = fmaxf(mrow[r], mt[r]);
            alpha[r] = __expf(mrow[r] - mnew);
            mrow[r] = mnew;
            tsum[r] = 0.f;
        }
#pragma unroll
        for (int t = 0; t < 4; ++t)
#pragma unroll
            for (int r = 0; r < 4; ++r) {
                float e = __expf(p[t][r] - mrow[r]);
                p[t][r] = e;
                tsum[r] += e;
            }
#pragma unroll
        for (int mask = 1; mask <= 8; mask <<= 1)
#pragma unroll
            for (int r = 0; r < 4; ++r)
                tsum[r] += __shfl_xor(tsum[r], mask, 64);
#pragma unroll
        for (int r = 0; r < 4; ++r)
            lrow[r] = lrow[r] * alpha[r] + tsum[r];
#pragma unroll
        for (int n = 0; n < 8; ++n)
#pragma unroll
            for (int r = 0; r < 4; ++r)
                o[n][r] = o[n][r] * alpha[r];

#pragma unroll
        for (int t = 0; t < 4; ++t)
#pragma unroll
            for (int r = 0; r < 4; ++r)
                myP[(kg * 4 + r) * PSTR + t * 16 + r16] = f2b(p[t][r]);
        asm volatile("s_waitcnt lgkmcnt(0)" ::: "memory");

#pragma unroll
        for (int kc = 0; kc < 2; ++kc) {
            bf16x8 pa = *(const bf16x8*)(myP + r16 * PSTR + kc * 32 + kg * 8);
#pragma unroll
            for (int n = 0; n < 8; ++n) {
                bf16x8 vb = *(const bf16x8*)(Vt + (n * 16 + r16) * VSTR + kc * 32 + kg * 8);
                o[n] = __builtin_amdgcn_mfma_f32_16x16x32_bf16(pa, vb, o[n], 0, 0, 0);
            }
        }
        BARRIER();                       // no vmcnt drain: keep prefetch in flight
    }
#undef PREF

#pragma unroll
    for (int n = 0; n < 8; ++n)
#pragma unroll
        for (int r = 0; r < 4; ++r) {
            int q = qbase + kg * 4 + r;
            aout[(size_t)q * HID + h * HDIM + n * 16 + r16] = f2b(o[n][r] / lrow[r]);
        }
}

extern "C" void kernel_launch(void* const* d_in, const int* in_sizes, int n_in,
                              void* d_out, int out_size, void* d_ws, size_t ws_size,
                              hipStream_t stream) {
    const float* hidden = (const float*)d_in[0];
    const float* cos_t = (const float*)d_in[2];
    const float* sin_t = (const float*)d_in[3];
    const float* q_w = (const float*)d_in[4];
    const float* q_b = (const float*)d_in[5];
    const float* k_w = (const float*)d_in[6];
    const float* k_b = (const float*)d_in[7];
    const float* v_w = (const float*)d_in[8];
    const float* v_b = (const float*)d_in[9];
    const float* o_w = (const float*)d_in[10];
    const float* o_b = (const float*)d_in[11];

    char* ws = (char*)d_ws;
    unsigned short* hbf  = (unsigned short*)ws;                   // 2048*4608 bf16
    unsigned short* attn = hbf;                                   // alias: reused after QKV GEMM
    unsigned short* wqkv = (unsigned short*)(ws + 18874368);      // 5632*4608 bf16 (dead after QKV GEMM)
    unsigned short* vtg  = wqkv;                                  // alias: V^T [4][128][2048]
    unsigned short* wo   = (unsigned short*)(ws + 70778880);      // 4608*4608 bf16
    unsigned short* qkv  = (unsigned short*)(ws + 113246208);     // 2048*5632 bf16

    dim3 blk(256);
    conv_all_kernel<<<4096, blk, 0, stream>>>(
        hidden, hbf,                          (SEQ * HID) / 4,
        q_w,    wqkv,                         (HID * HID) / 4,
        k_w,    wqkv + (size_t)HID * HID,     (512 * HID) / 4,
        v_w,    wqkv + (size_t)5120 * HID,    (512 * HID) / 4);

    // QKV GEMM on blocks 0..175; blocks 176..255 convert o_w concurrently.
    gemm256_kernel<<<dim3(256), dim3(512), 0, stream>>>(
        hbf, wqkv, qkv, q_b, k_b, v_b, NQKV, HID, 22, 176, 0,
        o_w, wo, (HID * HID) / 4);
    // fused RoPE + V-transpose (5120 rope blocks + 1024 vtrans blocks)
    rope_vt_kernel<<<6144, blk, 0, stream>>>(qkv, cos_t, sin_t, vtg);
    attn_kernel<<<dim3(NHEAD, SEQ / 64), blk, 0, stream>>>(qkv, vtg, attn);
    // O-proj: 128x192 tiles -> 16 x 24 = 384 blocks, 2 blocks/CU
    gemm_op_kernel<<<dim3(384), dim3(512), 0, stream>>>(
        attn, wo, (float*)d_out, o_b, HID, HID, 24);
}